// Round 8
// baseline (2746.170 us; speedup 1.0000x reference)
//
#include <hip/hip_runtime.h>
#include <cstdint>
#include <cstddef>

// Problem constants
#define BATCH  32
#define TSTEPS 1024
#define INDIM  512
#define HIDDIM 512
#define MTOT   (BATCH * TSTEPS)   // 32768 GEMM rows

// GEMM tiling: 128x128 tile, KC=16, double-buffered k-quad LDS
#define MB 128
#define NB 128
#define KC 16
#define KTILES (INDIM / KC)       // 32
#define NBLK   (HIDDIM / NB)      // 4

constexpr float ALPHA = 0.951229424500714f;  // exp(-1/20)

// f4-index swizzle (involution): spreads the 8-strided read addresses over
// distinct bank quads. Applied to BOTH the staging source row and the read
// index (rule #21: both-sides-or-neither with global_load_lds).
__device__ __forceinline__ int swz(int p) { return p ^ ((p >> 3) & 7); }

// ---------------------------------------------------------------------------
// Kernel 1: z = x * W^T (raw; bias added in scan). m97-style structure:
// global_load_lds staging (pre-swizzled per-lane source, linear LDS dest),
// double-buffered, raw s_barrier + counted vmcnt(4) so next-tile loads stay
// in flight across barriers. Zero ds_writes, zero staging registers.
// Per-output accumulation: single fmaf chain, k ascending -> bit-exact.
// TZ: write z transposed as zT[b][h][t] (for the streaming scan).
// ---------------------------------------------------------------------------
template <bool TZ>
__global__ __launch_bounds__(256, 4)
void snn_gemm(const float* __restrict__ x, const float* __restrict__ W,
              float* __restrict__ z)
{
    // [buf][kq][p'] ; slot (kq,p') holds row swz(p') k-quad kq
    __shared__ float4 Asm[2][KC / 4][MB];   // 2 x 8 KB
    __shared__ float4 Bsm[2][KC / 4][NB];   // 2 x 8 KB

    const int tid  = threadIdx.x;
    const int lane = tid & 63;
    const int wv   = tid >> 6;
    const int mb   = blockIdx.x / NBLK;
    const int nb   = blockIdx.x % NBLK;
    const int m0   = mb * MB;
    const int n0   = nb * NB;

    // staging map: wave wv handles slot-blocks sidx = wv and 4+wv.
    // slot s = sidx*64 + lane -> (kq = sidx>>1, p' = (sidx&1)*64 + lane),
    // source row = swz(p') (so that linear LDS write lands swizzled).
    int rows[2], kqS[2], s0q[2];
#pragma unroll
    for (int n = 0; n < 2; ++n) {
        const int sidx = n * 4 + wv;              // 0..7
        kqS[n] = sidx >> 1;                       // k-quad
        rows[n] = swz((sidx & 1) * 64 + lane);    // tile row
        s0q[n]  = sidx * 64;                      // wave-uniform slot base
    }

    // compute map: 8x8 sub-tile
    const int cm = (tid >> 4) * 8;
    const int cn = (tid & 15) * 8;
    int sma[8], smb[8];
#pragma unroll
    for (int i = 0; i < 8; ++i) { sma[i] = swz(cm + i); smb[i] = swz(cn + i); }

    float acc[8][8];
#pragma unroll
    for (int i = 0; i < 8; ++i)
#pragma unroll
        for (int j = 0; j < 8; ++j) acc[i][j] = 0.0f;

    auto issue = [&](int buf, int kt) {
#pragma unroll
        for (int n = 0; n < 2; ++n) {
            const float* ga = x + (size_t)(m0 + rows[n]) * INDIM + kt * KC + kqS[n] * 4;
            __builtin_amdgcn_global_load_lds(
                (const __attribute__((address_space(1))) void*)ga,
                (__attribute__((address_space(3))) void*)((char*)&Asm[buf][0][0] + s0q[n] * 16),
                16, 0, 0);
        }
#pragma unroll
        for (int n = 0; n < 2; ++n) {
            const float* gb = W + (size_t)(n0 + rows[n]) * INDIM + kt * KC + kqS[n] * 4;
            __builtin_amdgcn_global_load_lds(
                (const __attribute__((address_space(1))) void*)gb,
                (__attribute__((address_space(3))) void*)((char*)&Bsm[buf][0][0] + s0q[n] * 16),
                16, 0, 0);
        }
    };

    issue(0, 0);   // 4 loads in flight

    for (int kt = 0; kt < KTILES; ++kt) {
        const int buf = kt & 1;
        if (kt + 1 < KTILES) {
            issue(buf ^ 1, kt + 1);                         // +4 -> 8 outstanding
            asm volatile("s_waitcnt vmcnt(4)" ::: "memory"); // cur tile landed
        } else {
            asm volatile("s_waitcnt vmcnt(0)" ::: "memory");
        }
        __builtin_amdgcn_sched_barrier(0);
        __builtin_amdgcn_s_barrier();        // all waves' cur-tile loads done
        __builtin_amdgcn_sched_barrier(0);

#pragma unroll
        for (int kq = 0; kq < KC / 4; ++kq) {
            float4 bq[8];
#pragma unroll
            for (int j = 0; j < 8; ++j) bq[j] = Bsm[buf][kq][smb[j]];
#pragma unroll
            for (int i = 0; i < 8; ++i) {
                float4 aq = Asm[buf][kq][sma[i]];
#pragma unroll
                for (int j = 0; j < 8; ++j) {
                    acc[i][j] = fmaf(aq.x, bq[j].x, acc[i][j]);
                    acc[i][j] = fmaf(aq.y, bq[j].y, acc[i][j]);
                    acc[i][j] = fmaf(aq.z, bq[j].z, acc[i][j]);
                    acc[i][j] = fmaf(aq.w, bq[j].w, acc[i][j]);
                }
            }
        }

        __builtin_amdgcn_sched_barrier(0);
        __builtin_amdgcn_s_barrier();        // buf free for kt+1's issue target
        __builtin_amdgcn_sched_barrier(0);
    }

    if (TZ) {
        // zT[b][h][t]: row = n0+cn+j (h), cols t0+cm+i (t). i-quads -> float4.
        const int bi = m0 >> 10;            // batch (MB=128 divides 1024)
        const int t0 = (m0 & 1023) + cm;
#pragma unroll
        for (int j = 0; j < 8; ++j) {
            float* zr = z + ((size_t)bi * HIDDIM + n0 + cn + j) * TSTEPS + t0;
            float4 v0 = {acc[0][j], acc[1][j], acc[2][j], acc[3][j]};
            float4 v1 = {acc[4][j], acc[5][j], acc[6][j], acc[7][j]};
            *reinterpret_cast<float4*>(zr)     = v0;
            *reinterpret_cast<float4*>(zr + 4) = v1;
        }
    } else {
        // row-major z[m][n] (in-place fallback path)
#pragma unroll
        for (int i = 0; i < 8; ++i) {
            float* zr = z + (size_t)(m0 + cm + i) * HIDDIM + n0 + cn;
            float4 v0 = {acc[i][0], acc[i][1], acc[i][2], acc[i][3]};
            float4 v1 = {acc[i][4], acc[i][5], acc[i][6], acc[i][7]};
            *reinterpret_cast<float4*>(zr)     = v0;
            *reinterpret_cast<float4*>(zr + 4) = v1;
        }
    }
}

// ---------------------------------------------------------------------------
// Kernel 2: membrane scan over zT[b][h][t]. 256 blocks x 64 threads (one
// chain per lane, full chip). Loads are contiguous float4 streams per lane
// (perfect DRAM locality), ring of 16 f4 = 64 t-steps ahead, and the vmcnt
// FIFO holds ONLY loads: spikes are packed into bit-words (one u32 per 32
// steps) and expanded/stored in a separate phase after the serial chain.
// Chain arithmetic identical to all validated rounds -> bit-exact.
// ---------------------------------------------------------------------------
#define STEP(VE, BITW, BI)                                                   \
    { float zv = (VE) + bb; mem = fmaf(ALPHA, mem, zv);                      \
      bool s = (mem >= tt);                                                  \
      BITW |= s ? (1u << (BI)) : 0u;                                         \
      mem = s ? 0.0f : mem; }

#define PASS(P, REFILL)                                                      \
    { unsigned int w0 = 0, w1 = 0;                                          \
      _Pragma("unroll")                                                     \
      for (int r = 0; r < 16; ++r) {                                        \
          float4 v = pf[r];                                                 \
          if (REFILL) pf[r] = zp[((P) + 1) * 16 + r];                       \
          if (r < 8) {                                                      \
              STEP(v.x, w0, r * 4 + 0) STEP(v.y, w0, r * 4 + 1)             \
              STEP(v.z, w0, r * 4 + 2) STEP(v.w, w0, r * 4 + 3)             \
          } else {                                                          \
              STEP(v.x, w1, (r - 8) * 4 + 0) STEP(v.y, w1, (r - 8) * 4 + 1) \
              STEP(v.z, w1, (r - 8) * 4 + 2) STEP(v.w, w1, (r - 8) * 4 + 3) \
          }                                                                 \
      }                                                                     \
      wl[2 * (P) + 0][lane] = w0;                                           \
      wl[2 * (P) + 1][lane] = w1; }

__global__ __launch_bounds__(64)
void snn_scan_t(const float* __restrict__ zT, float* __restrict__ out,
                const float* __restrict__ bias, const float* __restrict__ thr)
{
    __shared__ unsigned int wl[32][64];   // packed spikes, 8 KB

    const int lane = threadIdx.x;
    const int b    = blockIdx.x >> 3;
    const int h0   = (blockIdx.x & 7) * 64;
    const int h    = h0 + lane;

    const float bb = bias[h];
    const float tt = thr[h];
    float mem = 0.0f;

    const float4* zp = reinterpret_cast<const float4*>(zT + ((size_t)b * HIDDIM + h) * TSTEPS);

    float4 pf[16];
#pragma unroll
    for (int r = 0; r < 16; ++r) pf[r] = zp[r];

    for (int p = 0; p < 15; ++p) { PASS(p, true) }
    PASS(15, false)

    // expansion phase: bits -> 0.0/1.0, coalesced 256B stores, no deps
    float* ob = out + (size_t)b * TSTEPS * HIDDIM + h;
#pragma unroll 2
    for (int w = 0; w < 32; ++w) {
        unsigned int bits = wl[w][lane];
        float* op = ob + (size_t)w * 32 * HIDDIM;
#pragma unroll
        for (int e = 0; e < 32; ++e)
            op[(size_t)e * HIDDIM] = ((bits >> e) & 1u) ? 1.0f : 0.0f;
    }

    out[(size_t)MTOT * HIDDIM + (size_t)b * HIDDIM + h] = mem;
}

// ---------------------------------------------------------------------------
// Fallback scan (ws too small -> z row-major, in-place in out). Round-2
// structure: 8-step group loads precede that group's stores -> in-place safe.
// ---------------------------------------------------------------------------
__global__ __launch_bounds__(64)
void snn_scan_fb(const float* zsrc, float* out,
                 const float* __restrict__ bias, const float* __restrict__ thr)
{
    const int h = (blockIdx.x & 7) * 64 + threadIdx.x;
    const int b = blockIdx.x >> 3;

    const float bb = bias[h];
    const float tt = thr[h];
    float mem = 0.0f;

    const size_t base = ((size_t)b * TSTEPS) * HIDDIM + h;
    const float* zp = zsrc + base;
    float* sp = out + base;

    for (int t = 0; t < TSTEPS; t += 8) {
        float zl[8];
#pragma unroll
        for (int j = 0; j < 8; ++j) zl[j] = zp[(size_t)(t + j) * HIDDIM];
#pragma unroll
        for (int j = 0; j < 8; ++j) {
            float zv = zl[j] + bb;
            mem = fmaf(ALPHA, mem, zv);
            bool s = (mem >= tt);
            sp[(size_t)(t + j) * HIDDIM] = s ? 1.0f : 0.0f;
            mem = s ? 0.0f : mem;
        }
    }
    out[(size_t)MTOT * HIDDIM + (size_t)b * HIDDIM + h] = mem;
}

extern "C" void kernel_launch(void* const* d_in, const int* in_sizes, int n_in,
                              void* d_out, int out_size, void* d_ws, size_t ws_size,
                              hipStream_t stream)
{
    const float* x    = (const float*)d_in[0];
    const float* W    = (const float*)d_in[1];
    const float* bias = (const float*)d_in[2];
    const float* thr  = (const float*)d_in[3];
    float* out = (float*)d_out;

    (void)in_sizes; (void)n_in; (void)out_size;

    const size_t z_bytes = (size_t)MTOT * HIDDIM * sizeof(float);  // 64 MB
    dim3 ggrid((MTOT / MB) * NBLK);      // 1024 blocks
    dim3 sgrid(BATCH * (HIDDIM / 64));   // 256 blocks

    if (ws_size >= z_bytes) {
        float* zT = (float*)d_ws;
        hipLaunchKernelGGL((snn_gemm<true>),  ggrid, dim3(256), 0, stream, x, W, zT);
        hipLaunchKernelGGL(snn_scan_t,        sgrid, dim3(64),  0, stream, zT, out, bias, thr);
    } else {
        hipLaunchKernelGGL((snn_gemm<false>), ggrid, dim3(256), 0, stream, x, W, out);
        hipLaunchKernelGGL(snn_scan_fb,       sgrid, dim3(64),  0, stream, out, out, bias, thr);
    }
}

// Round 10
// 1117.633 us; speedup vs baseline: 2.4571x; 2.4571x over previous
//
#include <hip/hip_runtime.h>
#include <cstdint>
#include <cstddef>

// Problem constants
#define BATCH  32
#define TSTEPS 1024
#define INDIM  512
#define HIDDIM 512
#define MTOT   (BATCH * TSTEPS)   // 32768 GEMM rows

// GEMM tiling (round-3 kernel, measured 217.5 us x3, absmax 0.0)
#define MB 128
#define NB 128
#define KC 32
#define KTILES (INDIM / KC)       // 16
#define NBLK   (HIDDIM / NB)      // 4

// Scan: 16 t-segments x 256 (b,h-tile) chains; 4096 one-wave blocks,
// ALL resident (64 thr, <=128 VGPR -> 4 waves/SIMD * 256 CU = 4096).
#define NSEG 16
#define SEGT (TSTEPS / NSEG)      // 64

constexpr float ALPHA = 0.951229424500714f;  // exp(-1/20)

__device__ __forceinline__ int swzg(int g) { return g ^ (g >> 3); }

// ---------------------------------------------------------------------------
// Kernel 1: z[m][n] = sum_k x[m][k] * W[n][k]  (raw; bias added in scan)
// Round-3 kernel verbatim. Ascending-k fmaf chain -> bit-exact.
// ---------------------------------------------------------------------------
__global__ __launch_bounds__(256)
void snn_gemm(const float* __restrict__ x, const float* __restrict__ W,
              float* __restrict__ z)
{
    __shared__ float Asm[KC][MB];   // 16 KB
    __shared__ float Bsm[KC][NB];   // 16 KB

    const int tid = threadIdx.x;
    const int mb  = blockIdx.x / NBLK;
    const int nb  = blockIdx.x % NBLK;
    const int m0  = mb * MB;
    const int n0  = nb * NB;

    const int sr = tid >> 1;           // 0..127
    const int sc = (tid & 1) * 4;      // f4 index 0 or 4
    const int srg = sr >> 2;
    const int swr = (swzg(srg) << 2) | (sr & 3);

    const float4* Ag = reinterpret_cast<const float4*>(x + (size_t)(m0 + sr) * INDIM) + sc;
    const float4* Bg = reinterpret_cast<const float4*>(W + (size_t)(n0 + sr) * INDIM) + sc;

    const int cm = (tid >> 4) * 8;
    const int cn = (tid & 15) * 8;
    const int am0 = swzg(cm >> 2), am1 = swzg((cm >> 2) + 1);
    const int bn0 = swzg(cn >> 2), bn1 = swzg((cn >> 2) + 1);

    float acc[8][8];
#pragma unroll
    for (int i = 0; i < 8; ++i)
#pragma unroll
        for (int j = 0; j < 8; ++j) acc[i][j] = 0.0f;

    float4 sa[4], sb[4];
#pragma unroll
    for (int j = 0; j < 4; ++j) { sa[j] = Ag[j]; sb[j] = Bg[j]; }

    for (int kt = 0; kt < KTILES; ++kt) {
        __syncthreads();
#pragma unroll
        for (int j = 0; j < 4; ++j) {
            const int kq = (sc + j) * 4;
            Asm[kq + 0][swr] = sa[j].x;
            Asm[kq + 1][swr] = sa[j].y;
            Asm[kq + 2][swr] = sa[j].z;
            Asm[kq + 3][swr] = sa[j].w;
            Bsm[kq + 0][swr] = sb[j].x;
            Bsm[kq + 1][swr] = sb[j].y;
            Bsm[kq + 2][swr] = sb[j].z;
            Bsm[kq + 3][swr] = sb[j].w;
        }
        __syncthreads();

        if (kt + 1 < KTILES) {
            Ag += KC / 4;
            Bg += KC / 4;
#pragma unroll
            for (int j = 0; j < 4; ++j) { sa[j] = Ag[j]; sb[j] = Bg[j]; }
        }

#pragma unroll 8
        for (int kc = 0; kc < KC; ++kc) {
            const float4* Ar = reinterpret_cast<const float4*>(&Asm[kc][0]);
            const float4* Br = reinterpret_cast<const float4*>(&Bsm[kc][0]);
            float4 a0 = Ar[am0];
            float4 a1 = Ar[am1];
            float4 b0 = Br[bn0];
            float4 b1 = Br[bn1];
            const float av[8] = {a0.x, a0.y, a0.z, a0.w, a1.x, a1.y, a1.z, a1.w};
            const float bv[8] = {b0.x, b0.y, b0.z, b0.w, b1.x, b1.y, b1.z, b1.w};
#pragma unroll
            for (int i = 0; i < 8; ++i)
#pragma unroll
                for (int j = 0; j < 8; ++j)
                    acc[i][j] = fmaf(av[i], bv[j], acc[i][j]);
        }
    }

#pragma unroll
    for (int i = 0; i < 8; ++i) {
        float* zr = z + (size_t)(m0 + cm + i) * HIDDIM + n0 + cn;
        float4 v0 = {acc[i][0], acc[i][1], acc[i][2], acc[i][3]};
        float4 v1 = {acc[i][4], acc[i][5], acc[i][6], acc[i][7]};
        *reinterpret_cast<float4*>(zr)     = v0;
        *reinterpret_cast<float4*>(zr + 4) = v1;
    }
}

// ---------------------------------------------------------------------------
// Kernel 2: segmented membrane scan with inter-block chaining.
// Grid = NSEG * 256 one-wave blocks, seg is the SLOWEST blockIdx dim.
// All 4096 waves are resident simultaneously (64 thr, __launch_bounds__
// caps VGPR <= 128 -> 4 waves/SIMD): the spin-wait cannot deadlock.
// Each block: (1) issue all 64 z-loads into registers (latency overlaps
// the spin), (2) acquire predecessor mem via agent-scope flag, (3) 64
// dependent steps in registers, spikes bit-packed, (4) release mem+flag,
// (5) expand spikes to memory OFF the critical path.
// Chain arithmetic identical to validated rounds -> bit-exact.
// ---------------------------------------------------------------------------
__global__ __launch_bounds__(64, 4)
void snn_scan_chain(const float* __restrict__ z, float* __restrict__ out,
                    const float* __restrict__ bias, const float* __restrict__ thr,
                    float* __restrict__ mem_buf, unsigned int* __restrict__ flags)
{
    const int lane = threadIdx.x;
    const int bid  = blockIdx.x;
    const int seg  = bid >> 8;          // 0..15, slowest
    const int bh   = bid & 255;         // b*8 + ht
    const int b    = bh >> 3;
    const int h0   = (bh & 7) * 64;
    const int h    = h0 + lane;
    const int cidx = bh * NSEG + seg;

    // (1) issue all z loads first; they drain while we spin
    const float* zp = z + ((size_t)b * TSTEPS + seg * SEGT) * HIDDIM + h;
    float zr[SEGT];
#pragma unroll
    for (int j = 0; j < SEGT; ++j) zr[j] = zp[(size_t)j * HIDDIM];

    const float bb = bias[h];
    const float tt = thr[h];

    // (2) acquire predecessor membrane state
    float mem = 0.0f;
    if (seg > 0) {
        const unsigned int* fp = &flags[cidx - 1];
        while (__hip_atomic_load(fp, __ATOMIC_ACQUIRE, __HIP_MEMORY_SCOPE_AGENT) == 0u)
            __builtin_amdgcn_s_sleep(8);
        mem = mem_buf[(size_t)(cidx - 1) * 64 + lane];
    }

    // (3) 64 serial steps, spikes packed into 2 bit-words
    unsigned int w0 = 0u, w1 = 0u;
#pragma unroll
    for (int j = 0; j < SEGT; ++j) {
        float zv = zr[j] + bb;
        mem = fmaf(ALPHA, mem, zv);
        bool s = (mem >= tt);
        if (j < 32) { w0 |= s ? (1u << j) : 0u; }
        else        { w1 |= s ? (1u << (j - 32)) : 0u; }
        mem = s ? 0.0f : mem;
    }

    // (4) hand off state immediately (successor proceeds while we store)
    if (seg + 1 < NSEG) {
        mem_buf[(size_t)cidx * 64 + lane] = mem;
        if (lane == 0)
            __hip_atomic_store(&flags[cidx], 1u, __ATOMIC_RELEASE,
                               __HIP_MEMORY_SCOPE_AGENT);
    } else {
        out[(size_t)MTOT * HIDDIM + (size_t)b * HIDDIM + h] = mem;
    }

    // (5) spike expansion: 64 coalesced 256B stores, off the critical path
    float* ob = out + ((size_t)b * TSTEPS + seg * SEGT) * HIDDIM + h;
#pragma unroll 8
    for (int j = 0; j < SEGT; ++j) {
        unsigned int bit = (j < 32) ? ((w0 >> j) & 1u) : ((w1 >> (j - 32)) & 1u);
        ob[(size_t)j * HIDDIM] = bit ? 1.0f : 0.0f;
    }
}

// ---------------------------------------------------------------------------
// Fallback scan (ws too small): round-2 in-place-safe structure.
// ---------------------------------------------------------------------------
__global__ __launch_bounds__(64)
void snn_scan_fb(const float* zsrc, float* out,
                 const float* __restrict__ bias, const float* __restrict__ thr)
{
    const int h = (blockIdx.x & 7) * 64 + threadIdx.x;
    const int b = blockIdx.x >> 3;

    const float bb = bias[h];
    const float tt = thr[h];
    float mem = 0.0f;

    const size_t base = ((size_t)b * TSTEPS) * HIDDIM + h;
    const float* zp = zsrc + base;
    float* sp = out + base;

    for (int t = 0; t < TSTEPS; t += 8) {
        float zl[8];
#pragma unroll
        for (int j = 0; j < 8; ++j) zl[j] = zp[(size_t)(t + j) * HIDDIM];
#pragma unroll
        for (int j = 0; j < 8; ++j) {
            float zv = zl[j] + bb;
            mem = fmaf(ALPHA, mem, zv);
            bool s = (mem >= tt);
            sp[(size_t)(t + j) * HIDDIM] = s ? 1.0f : 0.0f;
            mem = s ? 0.0f : mem;
        }
    }
    out[(size_t)MTOT * HIDDIM + (size_t)b * HIDDIM + h] = mem;
}

extern "C" void kernel_launch(void* const* d_in, const int* in_sizes, int n_in,
                              void* d_out, int out_size, void* d_ws, size_t ws_size,
                              hipStream_t stream)
{
    const float* x    = (const float*)d_in[0];
    const float* W    = (const float*)d_in[1];
    const float* bias = (const float*)d_in[2];
    const float* thr  = (const float*)d_in[3];
    float* out = (float*)d_out;

    (void)in_sizes; (void)n_in; (void)out_size;

    const size_t z_bytes    = (size_t)MTOT * HIDDIM * sizeof(float);       // 64 MB
    const size_t mem_bytes  = (size_t)256 * NSEG * 64 * sizeof(float);     // 1 MB
    const size_t flag_bytes = (size_t)256 * NSEG * sizeof(unsigned int);   // 16 KB
    const size_t need = z_bytes + mem_bytes + flag_bytes;

    dim3 ggrid((MTOT / MB) * NBLK);      // 1024 blocks

    if (ws_size >= need) {
        float* zbuf   = (float*)d_ws;
        float* membuf = (float*)((char*)d_ws + z_bytes);
        unsigned int* flags = (unsigned int*)((char*)d_ws + z_bytes + mem_bytes);

        // flags are poisoned 0xAA before every launch -> zero them (async, captured)
        hipMemsetAsync(flags, 0, flag_bytes, stream);

        hipLaunchKernelGGL(snn_gemm, ggrid, dim3(256), 0, stream, x, W, zbuf);
        hipLaunchKernelGGL(snn_scan_chain, dim3(NSEG * 256), dim3(64), 0, stream,
                           zbuf, out, bias, thr, membuf, flags);
    } else {
        hipLaunchKernelGGL(snn_gemm, ggrid, dim3(256), 0, stream, x, W, out);
        hipLaunchKernelGGL(snn_scan_fb, dim3(BATCH * 8), dim3(64), 0, stream,
                           out, out, bias, thr);
    }
}